// Round 3
// baseline (168.483 us; speedup 1.0000x reference)
//
#include <hip/hip_runtime.h>

// B=4, C=3, H=W=512, window=5 (fixed by setup_inputs).
#define Bd    4
#define Cc    3
#define Hd    512
#define Wd    512
#define WIN   5
#define PLANE (Hd * Wd)        // 1 MiB per f tap-plane (floats)

// Tile: full width (512) x TH=4 output rows per block; 256 threads,
// each thread computes 8 consecutive pixels x 3 channels of one row.
#define TH    4
#define LROWS (TH + 4)         // 8 staged rows (2-halo each side)
#define LROW  520              // LDS row stride (floats): col = gw + 4

typedef float f4 __attribute__((ext_vector_type(4)));

__global__ __launch_bounds__(256, 2) void filter_layer_kernel(
    const float* __restrict__ x,   // [B,3,H,W]
    const float* __restrict__ f,   // [B,25,H,W]
    float* __restrict__ y)         // [B,3,H,W]
{
    __shared__ __align__(16) float xs[Cc][LROWS][LROW];   // 49,920 B

    const int b   = blockIdx.y;
    const int h0  = blockIdx.x * TH;
    const int tid = threadIdx.x;

    // ---- Stage x rows [h0-2, h0+TH+2) for all 3 channels ----
    // 24 (c,row) rows of 512 floats; each row staged by 32 lanes as 4 f4
    // loads -> 12 fully-unrolled independent f4 loads per thread.
    {
        const int lane32 = tid & 31;
        const int rowi   = tid >> 5;                 // 0..7
        const int gh     = h0 + rowi - 2;
        const bool hok   = (gh >= 0) && (gh < Hd);
        #pragma unroll
        for (int c = 0; c < Cc; ++c) {
            const float* xrow = x + (((size_t)b * Cc + c) * Hd + gh) * Wd;
            #pragma unroll
            for (int g = 0; g < 4; ++g) {
                const int gw = (g * 32 + lane32) * 4;     // 0..508
                f4 v = {0.f, 0.f, 0.f, 0.f};
                if (hok) v = *(const f4*)(xrow + gw);
                *(f4*)&xs[c][rowi][gw + 4] = v;           // col = gw+4, aligned
            }
            if (lane32 == 0) {   // horizontal halo (image edge) = 0
                xs[c][rowi][2]   = 0.f; xs[c][rowi][3]   = 0.f;
                xs[c][rowi][516] = 0.f; xs[c][rowi][517] = 0.f;
            }
        }
    }
    __syncthreads();

    // ---- Compute: one output row per 64-lane wave, 8 px per lane ----
    const int lane = tid & 63;
    const int rw   = tid >> 6;            // 0..3 (output row within tile)
    const int h    = h0 + rw;
    const int px0  = lane * 8;            // wave covers the full 2KB row

    const float* fb = f + ((size_t)b * WIN * WIN) * PLANE
                        + (size_t)h * Wd + px0;

    float acc[Cc][8];
    #pragma unroll
    for (int c = 0; c < Cc; ++c)
        #pragma unroll
        for (int p = 0; p < 8; ++p) acc[c][p] = 0.f;

    // Rolling prefetch: tap-row i+1's ten f4 loads issued while computing
    // with tap-row i's values. Per wave each load is 1KB contiguous.
    f4 fc[2 * WIN], fn[2 * WIN];
    #pragma unroll
    for (int j = 0; j < WIN; ++j) {
        fc[2 * j]     = *(const f4*)(fb + (size_t)j * PLANE);
        fc[2 * j + 1] = *(const f4*)(fb + (size_t)j * PLANE + 4);
    }

    #pragma unroll 1
    for (int i = 0; i < WIN; ++i) {
        if (i + 1 < WIN) {
            const float* fr = fb + (size_t)(i + 1) * WIN * PLANE;
            #pragma unroll
            for (int j = 0; j < WIN; ++j) {
                fn[2 * j]     = *(const f4*)(fr + (size_t)j * PLANE);
                fn[2 * j + 1] = *(const f4*)(fr + (size_t)j * PLANE + 4);
            }
        }

        // x row segment: 16 floats/channel (4 aligned f4); window for
        // output px p, tap j is xr[p + j + 2]  (range 2..13 of 0..15).
        float xr[Cc][16];
        #pragma unroll
        for (int c = 0; c < Cc; ++c)
            #pragma unroll
            for (int g = 0; g < 4; ++g)
                *(f4*)&xr[c][g * 4] = *(const f4*)&xs[c][rw + i][px0 + g * 4];

        #pragma unroll
        for (int j = 0; j < WIN; ++j) {
            #pragma unroll
            for (int c = 0; c < Cc; ++c) {
                #pragma unroll
                for (int p = 0; p < 8; ++p) {
                    const float fv = (p < 4)
                        ? ((const float*)&fc[2 * j])[p]
                        : ((const float*)&fc[2 * j + 1])[p - 4];
                    acc[c][p] += fv * xr[c][p + j + 2];
                }
            }
        }

        #pragma unroll
        for (int t = 0; t < 2 * WIN; ++t) fc[t] = fn[t];
    }

    // ---- Store: 3 channels x 8 px (two aligned f4 each) ----
    #pragma unroll
    for (int c = 0; c < Cc; ++c) {
        float* yp = y + (((size_t)b * Cc + c) * Hd + h) * Wd + px0;
        f4 o0 = {acc[c][0], acc[c][1], acc[c][2], acc[c][3]};
        f4 o1 = {acc[c][4], acc[c][5], acc[c][6], acc[c][7]};
        *(f4*)yp       = o0;
        *(f4*)(yp + 4) = o1;
    }
}

extern "C" void kernel_launch(void* const* d_in, const int* in_sizes, int n_in,
                              void* d_out, int out_size, void* d_ws, size_t ws_size,
                              hipStream_t stream) {
    const float* x = (const float*)d_in[0];   // [4,3,512,512] fp32
    const float* f = (const float*)d_in[1];   // [4,25,512,512] fp32
    float* y = (float*)d_out;                 // [4,3,512,512] fp32

    dim3 grid(Hd / TH, Bd);                   // (128, 4) = 512 blocks
    filter_layer_kernel<<<grid, dim3(256), 0, stream>>>(x, f, y);
}

// Round 4
// 165.934 us; speedup vs baseline: 1.0154x; 1.0154x over previous
//
#include <hip/hip_runtime.h>

// B=4, C=3, H=W=512, window=5 (fixed by setup_inputs).
#define Bd    4
#define Cc    3
#define Hd    512
#define Wd    512
#define WIN   5
#define PLANE (Hd * Wd)        // 1 MiB per f tap-plane (floats)

typedef float f4 __attribute__((ext_vector_type(4)));

// LDS-free design: x (12.6 MB) lives in L1/L2/L3; each thread computes
// 4 px x 3 channels of one row. 128-thread blocks, one block per (h,b):
// 2048 blocks -> 8 blocks/CU = 16 waves/CU, no barriers, ~85 VGPR.
__global__ __launch_bounds__(128, 4) void filter_layer_kernel(
    const float* __restrict__ x,   // [B,3,H,W]
    const float* __restrict__ f,   // [B,25,H,W]
    float* __restrict__ y)         // [B,3,H,W]
{
    const int h   = blockIdx.x;
    const int b   = blockIdx.y;
    const int px0 = (int)threadIdx.x * 4;        // 0..508

    // f[b, k, h, px0..px0+3]; tap k plane stride = PLANE.
    const float* fb = f + ((size_t)b * (WIN * WIN)) * PLANE
                        + (size_t)h * Wd + px0;

    float acc[Cc][4] = {};

    const bool g0 = (px0 >= 4);          // left-edge guard (lane px0==0)
    const bool g2 = (px0 <= Wd - 8);     // right-edge guard (px0==508)

    // Double-buffered f stream: 5 f4 loads (one tap-row) in flight while
    // computing with the previous row. Per wave each load is 1KB contiguous.
    f4 fc[WIN], fn[WIN];
    #pragma unroll
    for (int j = 0; j < WIN; ++j)
        fc[j] = __builtin_nontemporal_load((const f4*)(fb + (size_t)j * PLANE));

    #pragma unroll 1
    for (int i = 0; i < WIN; ++i) {
        if (i + 1 < WIN) {
            const float* fr = fb + (size_t)(i + 1) * WIN * PLANE;
            #pragma unroll
            for (int j = 0; j < WIN; ++j)
                fn[j] = __builtin_nontemporal_load(
                    (const f4*)(fr + (size_t)j * PLANE));
        }

        const int  gh  = h + i - 2;
        const bool rok = (gh >= 0) && (gh < Hd);   // wave-uniform row guard

        #pragma unroll
        for (int c = 0; c < Cc; ++c) {
            // xr covers cols [px0-4, px0+8): 3 aligned f4 loads (L1/L2 hits).
            const float* xp = x + ((size_t)b * Cc + c) * PLANE
                                + (size_t)gh * Wd + px0;
            f4 x0 = {0.f, 0.f, 0.f, 0.f};
            f4 x1 = {0.f, 0.f, 0.f, 0.f};
            f4 x2 = {0.f, 0.f, 0.f, 0.f};
            if (rok) {
                x1 = *(const f4*)(xp);
                if (g0) x0 = *(const f4*)(xp - 4);
                if (g2) x2 = *(const f4*)(xp + 4);
            }
            float xr[12];
            *(f4*)&xr[0] = x0; *(f4*)&xr[4] = x1; *(f4*)&xr[8] = x2;

            // acc[c][p] += f[k=i*5+j][px0+p] * x[c][gh][px0+p+j-2]
            // x col index into xr: (p + j - 2) + 4 = p + j + 2  (2..9)
            #pragma unroll
            for (int j = 0; j < WIN; ++j) {
                acc[c][0] += fc[j].x * xr[j + 2];
                acc[c][1] += fc[j].y * xr[j + 3];
                acc[c][2] += fc[j].z * xr[j + 4];
                acc[c][3] += fc[j].w * xr[j + 5];
            }
        }

        #pragma unroll
        for (int j = 0; j < WIN; ++j) fc[j] = fn[j];
    }

    #pragma unroll
    for (int c = 0; c < Cc; ++c) {
        f4 o = {acc[c][0], acc[c][1], acc[c][2], acc[c][3]};
        __builtin_nontemporal_store(
            o, (f4*)(y + (((size_t)b * Cc + c) * Hd + h) * Wd + px0));
    }
}

extern "C" void kernel_launch(void* const* d_in, const int* in_sizes, int n_in,
                              void* d_out, int out_size, void* d_ws, size_t ws_size,
                              hipStream_t stream) {
    const float* x = (const float*)d_in[0];   // [4,3,512,512] fp32
    const float* f = (const float*)d_in[1];   // [4,25,512,512] fp32
    float* y = (float*)d_out;                 // [4,3,512,512] fp32

    dim3 grid(Hd, Bd);                        // one block per (h, b): 2048
    filter_layer_kernel<<<grid, dim3(128), 0, stream>>>(x, f, y);
}

// Round 5
// 165.101 us; speedup vs baseline: 1.0205x; 1.0050x over previous
//
#include <hip/hip_runtime.h>

// B=4, C=3, H=W=512, window=5 (fixed by setup_inputs).
#define Bd    4
#define Cc    3
#define Hd    512
#define Wd    512
#define WIN   5
#define PLANE (Hd * Wd)        // 1 MiB per f tap-plane (floats)

typedef float f4 __attribute__((ext_vector_type(4)));

// LDS-free, fully software-pipelined: both the f tap-row stream and the x
// row reads are double-buffered in registers, so iteration i computes with
// values issued at iteration i-1 while i+1's loads are in flight. No
// barriers. 2048 blocks x 128 threads; launch_bounds(128,3) -> 12 waves/CU.
__global__ __launch_bounds__(128, 3) void filter_layer_kernel(
    const float* __restrict__ x,   // [B,3,H,W]
    const float* __restrict__ f,   // [B,25,H,W]
    float* __restrict__ y)         // [B,3,H,W]
{
    const int h   = blockIdx.x;
    const int b   = blockIdx.y;
    const int px0 = (int)threadIdx.x * 4;        // 0..508

    const float* fb = f + ((size_t)b * (WIN * WIN)) * PLANE
                        + (size_t)h * Wd + px0;
    const float* xbase = x + (size_t)b * Cc * PLANE + px0;

    const bool g0 = (px0 >= 4);          // left-edge guard
    const bool g2 = (px0 <= Wd - 8);     // right-edge guard
    const f4 z = {0.f, 0.f, 0.f, 0.f};

    float acc[Cc][4] = {};

    // Double buffers: x row (3 f4/channel, cols px0-4 / px0 / px0+4) and
    // f tap-row (5 f4). ~145 VGPR live set.
    f4 xa[Cc][3], xn[Cc][3];
    f4 fc[WIN], fn[WIN];

    // ---- Prologue: loads for tap-row i=0 (x row gh = h-2) ----
    {
        const int  gh  = h - 2;
        const bool rok = (gh >= 0);
        #pragma unroll
        for (int c = 0; c < Cc; ++c) {
            const float* xp = xbase + (size_t)c * PLANE + (size_t)gh * Wd;
            xa[c][0] = (rok && g0) ? *(const f4*)(xp - 4) : z;
            xa[c][1] = rok         ? *(const f4*)(xp)     : z;
            xa[c][2] = (rok && g2) ? *(const f4*)(xp + 4) : z;
        }
        #pragma unroll
        for (int j = 0; j < WIN; ++j)
            fc[j] = __builtin_nontemporal_load(
                (const f4*)(fb + (size_t)j * PLANE));
    }

    #pragma unroll 1
    for (int i = 0; i < WIN; ++i) {
        // ---- Issue iteration i+1's loads first; they fly during compute ----
        if (i + 1 < WIN) {
            const int  gh  = h + i - 1;              // (i+1) - 2
            const bool rok = (gh >= 0) && (gh < Hd);
            #pragma unroll
            for (int c = 0; c < Cc; ++c) {
                const float* xp = xbase + (size_t)c * PLANE + (size_t)gh * Wd;
                xn[c][0] = (rok && g0) ? *(const f4*)(xp - 4) : z;
                xn[c][1] = rok         ? *(const f4*)(xp)     : z;
                xn[c][2] = (rok && g2) ? *(const f4*)(xp + 4) : z;
            }
            const float* fr = fb + (size_t)(i + 1) * WIN * PLANE;
            #pragma unroll
            for (int j = 0; j < WIN; ++j)
                fn[j] = __builtin_nontemporal_load(
                    (const f4*)(fr + (size_t)j * PLANE));
        }

        // ---- Compute tap-row i from xa/fc (loaded one iteration ago) ----
        #pragma unroll
        for (int c = 0; c < Cc; ++c) {
            float xr[12];
            *(f4*)&xr[0] = xa[c][0];
            *(f4*)&xr[4] = xa[c][1];
            *(f4*)&xr[8] = xa[c][2];
            // acc[c][p] += f[k=i*5+j][px0+p] * x[c][gh][px0+p+j-2]
            // xr index: (p + j - 2) + 4 = p + j + 2
            #pragma unroll
            for (int j = 0; j < WIN; ++j) {
                acc[c][0] += fc[j].x * xr[j + 2];
                acc[c][1] += fc[j].y * xr[j + 3];
                acc[c][2] += fc[j].z * xr[j + 4];
                acc[c][3] += fc[j].w * xr[j + 5];
            }
        }

        // ---- Rotate buffers ----
        #pragma unroll
        for (int c = 0; c < Cc; ++c) {
            xa[c][0] = xn[c][0]; xa[c][1] = xn[c][1]; xa[c][2] = xn[c][2];
        }
        #pragma unroll
        for (int j = 0; j < WIN; ++j) fc[j] = fn[j];
    }

    #pragma unroll
    for (int c = 0; c < Cc; ++c) {
        f4 o = {acc[c][0], acc[c][1], acc[c][2], acc[c][3]};
        __builtin_nontemporal_store(
            o, (f4*)(y + (((size_t)b * Cc + c) * Hd + h) * Wd + px0));
    }
}

extern "C" void kernel_launch(void* const* d_in, const int* in_sizes, int n_in,
                              void* d_out, int out_size, void* d_ws, size_t ws_size,
                              hipStream_t stream) {
    const float* x = (const float*)d_in[0];   // [4,3,512,512] fp32
    const float* f = (const float*)d_in[1];   // [4,25,512,512] fp32
    float* y = (float*)d_out;                 // [4,3,512,512] fp32

    dim3 grid(Hd, Bd);                        // one block per (h, b): 2048
    filter_layer_kernel<<<grid, dim3(128), 0, stream>>>(x, f, y);
}